// Round 1
// baseline (4478.700 us; speedup 1.0000x reference)
//
#include <hip/hip_runtime.h>
#include <hip/hip_bf16.h>

// Problem constants (match reference)
constexpr int N_NODES = 150000;
constexpr int N_EDGES = 2400000;
constexpr int D       = 128;
constexpr float LEAKY = 0.2f;
constexpr float L2EPS = 1e-12f;

// ---------------------------------------------------------------------------
// Kernel 1: scatter  side[row] += val * ego[col]
// One thread per (edge, 4-float chunk): 32 chunk-threads per edge.
// Lane layout: 32 consecutive threads cover one edge's 128 floats -> the
// gather of ego[col] row is a contiguous 512B burst per edge.
// ---------------------------------------------------------------------------
__global__ __launch_bounds__(256) void scatter_kernel(
    const int*   __restrict__ erow,
    const int*   __restrict__ ecol,
    const float* __restrict__ eval,
    const float* __restrict__ ego,
    float*       __restrict__ side) {
  long long t = (long long)blockIdx.x * blockDim.x + threadIdx.x;
  int e = (int)(t >> 5);
  if (e >= N_EDGES) return;
  int c = (int)(t & 31);            // chunk of 4 floats

  int r  = erow[e];
  int cl = ecol[e];
  float v = eval[e];

  const float4* src = (const float4*)(ego + (long long)cl * D);
  float4 m = src[c];

  float* dst = side + (long long)r * D + c * 4;
  atomicAdd(dst + 0, v * m.x);
  atomicAdd(dst + 1, v * m.y);
  atomicAdd(dst + 2, v * m.z);
  atomicAdd(dst + 3, v * m.w);
}

// ---------------------------------------------------------------------------
// Kernel 2: fused dual-GEMM + leaky_relu + add + row L2-normalize.
// Block = 128 threads (thread j owns output column j), RPB rows per block.
// side row and (ego*side) row staged in LDS; w_gc/w_bi streamed (coalesced,
// L2-resident: 2 x 64KB). LDS reads s_side[r][k] are wave-uniform broadcasts.
// ---------------------------------------------------------------------------
constexpr int RPB = 16;   // 150000 / 16 = 9375 blocks exactly

__global__ __launch_bounds__(128) void transform_kernel(
    const float* __restrict__ side,
    const float* __restrict__ ego,
    const float* __restrict__ w_gc,
    const float* __restrict__ b_gc,
    const float* __restrict__ w_bi,
    const float* __restrict__ b_bi,
    float*       __restrict__ out) {
  __shared__ float s_side[RPB][D];
  __shared__ float s_prod[RPB][D];
  __shared__ float s_part[RPB][2];

  const int j    = threadIdx.x;
  const int base = blockIdx.x * RPB;

  #pragma unroll
  for (int r = 0; r < RPB; ++r) {
    int node = base + r;
    float s = 0.f, e = 0.f;
    if (node < N_NODES) {
      s = side[(long long)node * D + j];
      e = ego [(long long)node * D + j];
    }
    s_side[r][j] = s;
    s_prod[r][j] = e * s;
  }
  __syncthreads();

  float acc_gc[RPB];
  float acc_bi[RPB];
  #pragma unroll
  for (int r = 0; r < RPB; ++r) { acc_gc[r] = 0.f; acc_bi[r] = 0.f; }

  for (int k = 0; k < D; ++k) {
    float wg = w_gc[k * D + j];
    float wb = w_bi[k * D + j];
    #pragma unroll
    for (int r = 0; r < RPB; ++r) {
      acc_gc[r] = fmaf(s_side[r][k], wg, acc_gc[r]);
      acc_bi[r] = fmaf(s_prod[r][k], wb, acc_bi[r]);
    }
  }

  const float bg = b_gc[j];
  const float bb = b_bi[j];

  #pragma unroll
  for (int r = 0; r < RPB; ++r) {
    float x1 = acc_gc[r] + bg; x1 = (x1 > 0.f) ? x1 : LEAKY * x1;
    float x2 = acc_bi[r] + bb; x2 = (x2 > 0.f) ? x2 : LEAKY * x2;
    acc_gc[r] = x1 + x2;        // reuse as the pre-norm row value
  }

  // Row-wise sum of squares over the 128 threads (2 waves).
  const int lane = j & 63;
  const int wv   = j >> 6;
  #pragma unroll
  for (int r = 0; r < RPB; ++r) {
    float sq = acc_gc[r] * acc_gc[r];
    #pragma unroll
    for (int off = 32; off > 0; off >>= 1) sq += __shfl_down(sq, off, 64);
    if (lane == 0) s_part[r][wv] = sq;
  }
  __syncthreads();

  #pragma unroll
  for (int r = 0; r < RPB; ++r) {
    int node = base + r;
    if (node < N_NODES) {
      float tot = s_part[r][0] + s_part[r][1];
      float inv = rsqrtf(fmaxf(tot, L2EPS));
      out[(long long)node * D + j] = acc_gc[r] * inv;
    }
  }
}

// ---------------------------------------------------------------------------
extern "C" void kernel_launch(void* const* d_in, const int* in_sizes, int n_in,
                              void* d_out, int out_size, void* d_ws, size_t ws_size,
                              hipStream_t stream) {
  const int*   erow = (const int*)  d_in[0];
  const int*   ecol = (const int*)  d_in[1];
  const float* eval = (const float*)d_in[2];
  const float* ego  = (const float*)d_in[3];
  const float* w_gc = (const float*)d_in[4];
  const float* b_gc = (const float*)d_in[5];
  const float* w_bi = (const float*)d_in[6];
  const float* b_bi = (const float*)d_in[7];
  float* out = (float*)d_out;

  const size_t side_bytes = (size_t)N_NODES * D * sizeof(float);
  // Prefer workspace; d_out is exactly [N, D] fp32 and is safe as a side
  // buffer (transform reads/writes the same rows block-locally).
  float* side = (ws_size >= side_bytes) ? (float*)d_ws : out;

  hipMemsetAsync(side, 0, side_bytes, stream);

  {
    long long total = (long long)N_EDGES * 32;
    int block = 256;
    int grid  = (int)((total + block - 1) / block);
    scatter_kernel<<<grid, block, 0, stream>>>(erow, ecol, eval, ego, side);
  }
  {
    int grid = (N_NODES + RPB - 1) / RPB;
    transform_kernel<<<grid, 128, 0, stream>>>(side, ego, w_gc, b_gc, w_bi, b_bi, out);
  }
}

// Round 2
// 846.111 us; speedup vs baseline: 5.2933x; 5.2933x over previous
//
#include <hip/hip_runtime.h>
#include <hip/hip_bf16.h>

constexpr int N_NODES = 150000;
constexpr int N_EDGES = 2400000;
constexpr int D       = 128;
constexpr float LEAKY = 0.2f;
constexpr float L2EPS = 1e-12f;

constexpr int RPB     = 16;                      // rows per block in fused/transform
constexpr int NB_SCAN = (N_NODES + 255) / 256;   // 586 (<1024)

// ===========================================================================
// Counting-sort passes
// ===========================================================================
__global__ __launch_bounds__(256) void hist_kernel(
    const int* __restrict__ erow, int* __restrict__ cnt) {
  int e = blockIdx.x * 256 + threadIdx.x;
  if (e < N_EDGES) atomicAdd(&cnt[erow[e]], 1);
}

__global__ __launch_bounds__(256) void scan_block_sums(
    const int* __restrict__ cnt, int* __restrict__ bsums) {
  __shared__ int s[256];
  int i = blockIdx.x * 256 + threadIdx.x;
  s[threadIdx.x] = (i < N_NODES) ? cnt[i] : 0;
  __syncthreads();
  for (int off = 128; off > 0; off >>= 1) {
    if (threadIdx.x < off) s[threadIdx.x] += s[threadIdx.x + off];
    __syncthreads();
  }
  if (threadIdx.x == 0) bsums[blockIdx.x] = s[0];
}

__global__ __launch_bounds__(1024) void scan_partials(int* __restrict__ bsums) {
  __shared__ int s[1024];
  int v = (threadIdx.x < NB_SCAN) ? bsums[threadIdx.x] : 0;
  s[threadIdx.x] = v;
  __syncthreads();
  for (int off = 1; off < 1024; off <<= 1) {
    int t = (threadIdx.x >= off) ? s[threadIdx.x - off] : 0;
    __syncthreads();
    s[threadIdx.x] += t;
    __syncthreads();
  }
  if (threadIdx.x < NB_SCAN) bsums[threadIdx.x] = s[threadIdx.x] - v;  // exclusive
}

__global__ __launch_bounds__(256) void scan_final(
    const int* __restrict__ cnt, const int* __restrict__ bsums,
    int* __restrict__ offs, int* __restrict__ cursor) {
  __shared__ int s[256];
  int i = blockIdx.x * 256 + threadIdx.x;
  int v = (i < N_NODES) ? cnt[i] : 0;
  s[threadIdx.x] = v;
  __syncthreads();
  for (int off = 1; off < 256; off <<= 1) {
    int t = (threadIdx.x >= off) ? s[threadIdx.x - off] : 0;
    __syncthreads();
    s[threadIdx.x] += t;
    __syncthreads();
  }
  if (i < N_NODES) {
    int excl = s[threadIdx.x] - v + bsums[blockIdx.x];
    offs[i]   = excl;
    cursor[i] = excl;
  }
  if (i == 0) offs[N_NODES] = N_EDGES;
}

__global__ __launch_bounds__(256) void bin_kernel(
    const int*   __restrict__ erow,
    const int*   __restrict__ ecol,
    const float* __restrict__ eval,
    int*         __restrict__ cursor,
    int*         __restrict__ sorted_col,
    float*       __restrict__ sorted_val) {
  int e = blockIdx.x * 256 + threadIdx.x;
  if (e >= N_EDGES) return;
  int r = erow[e];
  int pos = atomicAdd(&cursor[r], 1);
  sorted_col[pos] = ecol[e];
  sorted_val[pos] = eval[e];
}

// ===========================================================================
// Fused pull-SpMM + dual-GEMM + leaky_relu + add + L2-normalize
// Block = 128 threads (thread j owns column j), RPB rows per block.
// ===========================================================================
__global__ __launch_bounds__(128) void fused_kernel(
    const int*   __restrict__ offs,
    const int*   __restrict__ sorted_col,
    const float* __restrict__ sorted_val,
    const float* __restrict__ ego,
    const float* __restrict__ w_gc,
    const float* __restrict__ b_gc,
    const float* __restrict__ w_bi,
    const float* __restrict__ b_bi,
    float*       __restrict__ out) {
  __shared__ float s_side[RPB][D];
  __shared__ float s_prod[RPB][D];
  __shared__ float s_part[RPB][2];

  const int j    = threadIdx.x;
  const int base = blockIdx.x * RPB;

  // Phase 1: pull-SpMM for this block's rows
  for (int r = 0; r < RPB; ++r) {
    int node = base + r;
    float acc = 0.f, e = 0.f;
    if (node < N_NODES) {
      int s0 = offs[node], s1 = offs[node + 1];
      int i = s0;
      for (; i + 4 <= s1; i += 4) {
        int   c0 = sorted_col[i],     c1 = sorted_col[i + 1];
        int   c2 = sorted_col[i + 2], c3 = sorted_col[i + 3];
        float v0 = sorted_val[i],     v1 = sorted_val[i + 1];
        float v2 = sorted_val[i + 2], v3 = sorted_val[i + 3];
        float g0 = ego[(long long)c0 * D + j];
        float g1 = ego[(long long)c1 * D + j];
        float g2 = ego[(long long)c2 * D + j];
        float g3 = ego[(long long)c3 * D + j];
        acc = fmaf(v0, g0, acc);
        acc = fmaf(v1, g1, acc);
        acc = fmaf(v2, g2, acc);
        acc = fmaf(v3, g3, acc);
      }
      for (; i < s1; ++i) {
        int   c = sorted_col[i];
        float v = sorted_val[i];
        acc = fmaf(v, ego[(long long)c * D + j], acc);
      }
      e = ego[(long long)node * D + j];
    }
    s_side[r][j] = acc;
    s_prod[r][j] = e * acc;
  }
  __syncthreads();

  // Phase 2: dual GEMM
  float acc_gc[RPB];
  float acc_bi[RPB];
  #pragma unroll
  for (int r = 0; r < RPB; ++r) { acc_gc[r] = 0.f; acc_bi[r] = 0.f; }

  for (int k = 0; k < D; ++k) {
    float wg = w_gc[k * D + j];
    float wb = w_bi[k * D + j];
    #pragma unroll
    for (int r = 0; r < RPB; ++r) {
      acc_gc[r] = fmaf(s_side[r][k], wg, acc_gc[r]);
      acc_bi[r] = fmaf(s_prod[r][k], wb, acc_bi[r]);
    }
  }

  const float bg = b_gc[j];
  const float bb = b_bi[j];

  #pragma unroll
  for (int r = 0; r < RPB; ++r) {
    float x1 = acc_gc[r] + bg; x1 = (x1 > 0.f) ? x1 : LEAKY * x1;
    float x2 = acc_bi[r] + bb; x2 = (x2 > 0.f) ? x2 : LEAKY * x2;
    acc_gc[r] = x1 + x2;
  }

  // Phase 3: row L2-normalize (128 threads = 2 waves per row value set)
  const int lane = j & 63;
  const int wv   = j >> 6;
  #pragma unroll
  for (int r = 0; r < RPB; ++r) {
    float sq = acc_gc[r] * acc_gc[r];
    #pragma unroll
    for (int off = 32; off > 0; off >>= 1) sq += __shfl_down(sq, off, 64);
    if (lane == 0) s_part[r][wv] = sq;
  }
  __syncthreads();

  #pragma unroll
  for (int r = 0; r < RPB; ++r) {
    int node = base + r;
    if (node < N_NODES) {
      float tot = s_part[r][0] + s_part[r][1];
      float inv = rsqrtf(fmaxf(tot, L2EPS));
      out[(long long)node * D + j] = acc_gc[r] * inv;
    }
  }
}

// ===========================================================================
// Fallback path (round-1): atomic scatter + separate transform (small ws)
// ===========================================================================
__global__ __launch_bounds__(256) void scatter_kernel(
    const int*   __restrict__ erow,
    const int*   __restrict__ ecol,
    const float* __restrict__ eval,
    const float* __restrict__ ego,
    float*       __restrict__ side) {
  long long t = (long long)blockIdx.x * blockDim.x + threadIdx.x;
  int e = (int)(t >> 5);
  if (e >= N_EDGES) return;
  int c = (int)(t & 31);
  int r  = erow[e];
  int cl = ecol[e];
  float v = eval[e];
  const float4* src = (const float4*)(ego + (long long)cl * D);
  float4 m = src[c];
  float* dst = side + (long long)r * D + c * 4;
  atomicAdd(dst + 0, v * m.x);
  atomicAdd(dst + 1, v * m.y);
  atomicAdd(dst + 2, v * m.z);
  atomicAdd(dst + 3, v * m.w);
}

__global__ __launch_bounds__(128) void transform_kernel(
    const float* __restrict__ side,
    const float* __restrict__ ego,
    const float* __restrict__ w_gc,
    const float* __restrict__ b_gc,
    const float* __restrict__ w_bi,
    const float* __restrict__ b_bi,
    float*       __restrict__ out) {
  __shared__ float s_side[RPB][D];
  __shared__ float s_prod[RPB][D];
  __shared__ float s_part[RPB][2];
  const int j    = threadIdx.x;
  const int base = blockIdx.x * RPB;
  #pragma unroll
  for (int r = 0; r < RPB; ++r) {
    int node = base + r;
    float s = 0.f, e = 0.f;
    if (node < N_NODES) {
      s = side[(long long)node * D + j];
      e = ego [(long long)node * D + j];
    }
    s_side[r][j] = s;
    s_prod[r][j] = e * s;
  }
  __syncthreads();
  float acc_gc[RPB], acc_bi[RPB];
  #pragma unroll
  for (int r = 0; r < RPB; ++r) { acc_gc[r] = 0.f; acc_bi[r] = 0.f; }
  for (int k = 0; k < D; ++k) {
    float wg = w_gc[k * D + j];
    float wb = w_bi[k * D + j];
    #pragma unroll
    for (int r = 0; r < RPB; ++r) {
      acc_gc[r] = fmaf(s_side[r][k], wg, acc_gc[r]);
      acc_bi[r] = fmaf(s_prod[r][k], wb, acc_bi[r]);
    }
  }
  const float bg = b_gc[j];
  const float bb = b_bi[j];
  #pragma unroll
  for (int r = 0; r < RPB; ++r) {
    float x1 = acc_gc[r] + bg; x1 = (x1 > 0.f) ? x1 : LEAKY * x1;
    float x2 = acc_bi[r] + bb; x2 = (x2 > 0.f) ? x2 : LEAKY * x2;
    acc_gc[r] = x1 + x2;
  }
  const int lane = j & 63;
  const int wv   = j >> 6;
  #pragma unroll
  for (int r = 0; r < RPB; ++r) {
    float sq = acc_gc[r] * acc_gc[r];
    #pragma unroll
    for (int off = 32; off > 0; off >>= 1) sq += __shfl_down(sq, off, 64);
    if (lane == 0) s_part[r][wv] = sq;
  }
  __syncthreads();
  #pragma unroll
  for (int r = 0; r < RPB; ++r) {
    int node = base + r;
    if (node < N_NODES) {
      float tot = s_part[r][0] + s_part[r][1];
      float inv = rsqrtf(fmaxf(tot, L2EPS));
      out[(long long)node * D + j] = acc_gc[r] * inv;
    }
  }
}

// ===========================================================================
extern "C" void kernel_launch(void* const* d_in, const int* in_sizes, int n_in,
                              void* d_out, int out_size, void* d_ws, size_t ws_size,
                              hipStream_t stream) {
  const int*   erow = (const int*)  d_in[0];
  const int*   ecol = (const int*)  d_in[1];
  const float* eval = (const float*)d_in[2];
  const float* ego  = (const float*)d_in[3];
  const float* w_gc = (const float*)d_in[4];
  const float* b_gc = (const float*)d_in[5];
  const float* w_bi = (const float*)d_in[6];
  const float* b_bi = (const float*)d_in[7];
  float* out = (float*)d_out;

  // Workspace layout for the sort path
  auto align256 = [](size_t x) { return (x + 255) & ~(size_t)255; };
  size_t off_cnt    = 0;
  size_t off_offs   = align256(off_cnt    + (size_t)N_NODES * 4);
  size_t off_cursor = align256(off_offs   + (size_t)(N_NODES + 1) * 4);
  size_t off_bsums  = align256(off_cursor + (size_t)N_NODES * 4);
  size_t off_scol   = align256(off_bsums  + 1024 * 4);
  size_t off_sval   = align256(off_scol   + (size_t)N_EDGES * 4);
  size_t ws_needed  = off_sval + (size_t)N_EDGES * 4;

  if (ws_size >= ws_needed) {
    char* ws = (char*)d_ws;
    int*   cnt        = (int*)  (ws + off_cnt);
    int*   offs       = (int*)  (ws + off_offs);
    int*   cursor     = (int*)  (ws + off_cursor);
    int*   bsums      = (int*)  (ws + off_bsums);
    int*   sorted_col = (int*)  (ws + off_scol);
    float* sorted_val = (float*)(ws + off_sval);

    hipMemsetAsync(cnt, 0, (size_t)N_NODES * 4, stream);

    int eg = (N_EDGES + 255) / 256;
    hist_kernel<<<eg, 256, 0, stream>>>(erow, cnt);
    scan_block_sums<<<NB_SCAN, 256, 0, stream>>>(cnt, bsums);
    scan_partials<<<1, 1024, 0, stream>>>(bsums);
    scan_final<<<NB_SCAN, 256, 0, stream>>>(cnt, bsums, offs, cursor);
    bin_kernel<<<eg, 256, 0, stream>>>(erow, ecol, eval, cursor,
                                       sorted_col, sorted_val);
    int fg = (N_NODES + RPB - 1) / RPB;
    fused_kernel<<<fg, 128, 0, stream>>>(offs, sorted_col, sorted_val, ego,
                                         w_gc, b_gc, w_bi, b_bi, out);
  } else {
    // Fallback: atomic scatter into d_out as side buffer
    const size_t side_bytes = (size_t)N_NODES * D * sizeof(float);
    float* side = (ws_size >= side_bytes) ? (float*)d_ws : out;
    hipMemsetAsync(side, 0, side_bytes, stream);
    long long total = (long long)N_EDGES * 32;
    int grid = (int)((total + 255) / 256);
    scatter_kernel<<<grid, 256, 0, stream>>>(erow, ecol, eval, ego, side);
    int fg = (N_NODES + RPB - 1) / RPB;
    transform_kernel<<<fg, 128, 0, stream>>>(side, ego, w_gc, b_gc, w_bi, b_bi, out);
  }
}

// Round 3
// 743.862 us; speedup vs baseline: 6.0209x; 1.1375x over previous
//
#include <hip/hip_runtime.h>
#include <hip/hip_bf16.h>

constexpr int N_NODES = 150000;
constexpr int N_EDGES = 2400000;
constexpr int D       = 128;
constexpr float LEAKY = 0.2f;
constexpr float L2EPS = 1e-12f;

constexpr int NB_SCAN = (N_NODES + 255) / 256;   // 586 (<1024)

// ===========================================================================
// Counting-sort passes
// ===========================================================================
__global__ __launch_bounds__(256) void hist_kernel(
    const int* __restrict__ erow, int* __restrict__ cnt) {
  int e = blockIdx.x * 256 + threadIdx.x;
  if (e < N_EDGES) atomicAdd(&cnt[erow[e]], 1);
}

__global__ __launch_bounds__(256) void scan_block_sums(
    const int* __restrict__ cnt, int* __restrict__ bsums) {
  __shared__ int s[256];
  int i = blockIdx.x * 256 + threadIdx.x;
  s[threadIdx.x] = (i < N_NODES) ? cnt[i] : 0;
  __syncthreads();
  for (int off = 128; off > 0; off >>= 1) {
    if (threadIdx.x < off) s[threadIdx.x] += s[threadIdx.x + off];
    __syncthreads();
  }
  if (threadIdx.x == 0) bsums[blockIdx.x] = s[0];
}

__global__ __launch_bounds__(1024) void scan_partials(int* __restrict__ bsums) {
  __shared__ int s[1024];
  int v = (threadIdx.x < NB_SCAN) ? bsums[threadIdx.x] : 0;
  s[threadIdx.x] = v;
  __syncthreads();
  for (int off = 1; off < 1024; off <<= 1) {
    int t = (threadIdx.x >= off) ? s[threadIdx.x - off] : 0;
    __syncthreads();
    s[threadIdx.x] += t;
    __syncthreads();
  }
  if (threadIdx.x < NB_SCAN) bsums[threadIdx.x] = s[threadIdx.x] - v;  // exclusive
}

__global__ __launch_bounds__(256) void scan_final(
    const int* __restrict__ cnt, const int* __restrict__ bsums,
    int* __restrict__ offs, int* __restrict__ cursor) {
  __shared__ int s[256];
  int i = blockIdx.x * 256 + threadIdx.x;
  int v = (i < N_NODES) ? cnt[i] : 0;
  s[threadIdx.x] = v;
  __syncthreads();
  for (int off = 1; off < 256; off <<= 1) {
    int t = (threadIdx.x >= off) ? s[threadIdx.x - off] : 0;
    __syncthreads();
    s[threadIdx.x] += t;
    __syncthreads();
  }
  if (i < N_NODES) {
    int excl = s[threadIdx.x] - v + bsums[blockIdx.x];
    offs[i]   = excl;
    cursor[i] = excl;
  }
  if (i == 0) offs[N_NODES] = N_EDGES;
}

__global__ __launch_bounds__(256) void bin_kernel(
    const int*   __restrict__ erow,
    const int*   __restrict__ ecol,
    const float* __restrict__ eval,
    int*         __restrict__ cursor,
    int2*        __restrict__ sorted_ev) {
  int e = blockIdx.x * 256 + threadIdx.x;
  if (e >= N_EDGES) return;
  int r = erow[e];
  int pos = atomicAdd(&cursor[r], 1);
  sorted_ev[pos] = make_int2(ecol[e], __float_as_int(eval[e]));
}

// ===========================================================================
// Kernel A: pull-SpMM.  One row per 32-lane group, float4 gather per lane.
// 256-thread block = 8 groups.  grid = 150000/8 = 18750 (exact).
// ===========================================================================
__global__ __launch_bounds__(256) void spmm_kernel(
    const int*  __restrict__ offs,
    const int2* __restrict__ ev,
    const float* __restrict__ ego,
    float*       __restrict__ side) {
  const int t = threadIdx.x;
  const int g = t >> 5;
  const int l = t & 31;
  const int row = blockIdx.x * 8 + g;
  if (row >= N_NODES) return;

  const int s0 = offs[row], s1 = offs[row + 1];
  float ax = 0.f, ay = 0.f, az = 0.f, aw = 0.f;

  int i = s0;
  const int n4 = s0 + ((s1 - s0) & ~3);
  for (; i < n4; i += 4) {
    int2 e0 = ev[i], e1 = ev[i + 1], e2 = ev[i + 2], e3 = ev[i + 3];
    float4 g0 = *(const float4*)(ego + (size_t)e0.x * D + 4 * l);
    float4 g1 = *(const float4*)(ego + (size_t)e1.x * D + 4 * l);
    float4 g2 = *(const float4*)(ego + (size_t)e2.x * D + 4 * l);
    float4 g3 = *(const float4*)(ego + (size_t)e3.x * D + 4 * l);
    float v0 = __int_as_float(e0.y), v1 = __int_as_float(e1.y);
    float v2 = __int_as_float(e2.y), v3 = __int_as_float(e3.y);
    ax = fmaf(v0, g0.x, ax); ay = fmaf(v0, g0.y, ay);
    az = fmaf(v0, g0.z, az); aw = fmaf(v0, g0.w, aw);
    ax = fmaf(v1, g1.x, ax); ay = fmaf(v1, g1.y, ay);
    az = fmaf(v1, g1.z, az); aw = fmaf(v1, g1.w, aw);
    ax = fmaf(v2, g2.x, ax); ay = fmaf(v2, g2.y, ay);
    az = fmaf(v2, g2.z, az); aw = fmaf(v2, g2.w, aw);
    ax = fmaf(v3, g3.x, ax); ay = fmaf(v3, g3.y, ay);
    az = fmaf(v3, g3.z, az); aw = fmaf(v3, g3.w, aw);
  }
  for (; i < s1; ++i) {
    int2 e = ev[i];
    float4 gg = *(const float4*)(ego + (size_t)e.x * D + 4 * l);
    float v = __int_as_float(e.y);
    ax = fmaf(v, gg.x, ax); ay = fmaf(v, gg.y, ay);
    az = fmaf(v, gg.z, az); aw = fmaf(v, gg.w, aw);
  }

  float4 res = make_float4(ax, ay, az, aw);
  *(float4*)(side + (size_t)row * D + 4 * l) = res;
}

// ===========================================================================
// Kernel B: dual-GEMM + leaky_relu + add + L2-normalize.
// Block = 128 threads = 4 groups of 32 lanes.  Group q owns rows 4q..4q+3;
// lane l owns columns 4l..4l+3 (float4 accumulators).  Weights staged in LDS
// in 16-k tiles; all LDS reads are b128.  side may alias out (each block
// reads exactly the rows it later writes).
// ===========================================================================
constexpr int RPB2 = 16;   // 150000/16 = 9375 blocks (exact)
constexpr int WT   = 16;   // k-tile

__global__ __launch_bounds__(128) void transform_kernel(
    const float* __restrict__ side,
    const float* __restrict__ ego,
    const float* __restrict__ w_gc,
    const float* __restrict__ b_gc,
    const float* __restrict__ w_bi,
    const float* __restrict__ b_bi,
    float*       __restrict__ out) {
  __shared__ float s_side[RPB2][D];
  __shared__ float s_prod[RPB2][D];
  __shared__ float s_wg[WT][D];
  __shared__ float s_wb[WT][D];

  const int t = threadIdx.x;
  const int q = t >> 5;
  const int l = t & 31;
  const int base = blockIdx.x * RPB2;

  // Stage side rows + ego*side rows (float4, coalesced).
  // 16 rows x 32 float4s = 512 float4 slots / 128 threads = 4 each.
  #pragma unroll
  for (int it = 0; it < 4; ++it) {
    int f  = it * 128 + t;        // float4 slot
    int r  = f >> 5;
    int cc = (f & 31) * 4;
    float4 sv = *(const float4*)(side + (size_t)(base + r) * D + cc);
    float4 evv = *(const float4*)(ego + (size_t)(base + r) * D + cc);
    *(float4*)&s_side[r][cc] = sv;
    float4 pv = make_float4(sv.x * evv.x, sv.y * evv.y, sv.z * evv.z, sv.w * evv.w);
    *(float4*)&s_prod[r][cc] = pv;
  }

  float4 ag[4], ab[4];
  #pragma unroll
  for (int r = 0; r < 4; ++r) {
    ag[r] = make_float4(0.f, 0.f, 0.f, 0.f);
    ab[r] = make_float4(0.f, 0.f, 0.f, 0.f);
  }
  const int r0 = q * 4;

  for (int kt = 0; kt < D; kt += WT) {
    __syncthreads();   // previous tile consumed (also orders s_side staging)
    // Stage weight tile: WT rows x 32 float4 x 2 arrays; WT*32/128 = 4 slots each
    #pragma unroll
    for (int it = 0; it < (WT * 32) / 128; ++it) {
      int f  = it * 128 + t;
      int kr = f >> 5;
      int cc = (f & 31) * 4;
      *(float4*)&s_wg[kr][cc] = *(const float4*)(w_gc + (size_t)(kt + kr) * D + cc);
      *(float4*)&s_wb[kr][cc] = *(const float4*)(w_bi + (size_t)(kt + kr) * D + cc);
    }
    __syncthreads();

    #pragma unroll
    for (int kk = 0; kk < WT; kk += 4) {
      float4 wg0 = *(const float4*)&s_wg[kk + 0][4 * l];
      float4 wg1 = *(const float4*)&s_wg[kk + 1][4 * l];
      float4 wg2 = *(const float4*)&s_wg[kk + 2][4 * l];
      float4 wg3 = *(const float4*)&s_wg[kk + 3][4 * l];
      float4 wb0 = *(const float4*)&s_wb[kk + 0][4 * l];
      float4 wb1 = *(const float4*)&s_wb[kk + 1][4 * l];
      float4 wb2 = *(const float4*)&s_wb[kk + 2][4 * l];
      float4 wb3 = *(const float4*)&s_wb[kk + 3][4 * l];
      #pragma unroll
      for (int rr = 0; rr < 4; ++rr) {
        float4 sv = *(const float4*)&s_side[r0 + rr][kt + kk];  // 4 k vals (uniform in group)
        float4 pv = *(const float4*)&s_prod[r0 + rr][kt + kk];
        ag[rr].x = fmaf(sv.x, wg0.x, ag[rr].x); ag[rr].y = fmaf(sv.x, wg0.y, ag[rr].y);
        ag[rr].z = fmaf(sv.x, wg0.z, ag[rr].z); ag[rr].w = fmaf(sv.x, wg0.w, ag[rr].w);
        ag[rr].x = fmaf(sv.y, wg1.x, ag[rr].x); ag[rr].y = fmaf(sv.y, wg1.y, ag[rr].y);
        ag[rr].z = fmaf(sv.y, wg1.z, ag[rr].z); ag[rr].w = fmaf(sv.y, wg1.w, ag[rr].w);
        ag[rr].x = fmaf(sv.z, wg2.x, ag[rr].x); ag[rr].y = fmaf(sv.z, wg2.y, ag[rr].y);
        ag[rr].z = fmaf(sv.z, wg2.z, ag[rr].z); ag[rr].w = fmaf(sv.z, wg2.w, ag[rr].w);
        ag[rr].x = fmaf(sv.w, wg3.x, ag[rr].x); ag[rr].y = fmaf(sv.w, wg3.y, ag[rr].y);
        ag[rr].z = fmaf(sv.w, wg3.z, ag[rr].z); ag[rr].w = fmaf(sv.w, wg3.w, ag[rr].w);
        ab[rr].x = fmaf(pv.x, wb0.x, ab[rr].x); ab[rr].y = fmaf(pv.x, wb0.y, ab[rr].y);
        ab[rr].z = fmaf(pv.x, wb0.z, ab[rr].z); ab[rr].w = fmaf(pv.x, wb0.w, ab[rr].w);
        ab[rr].x = fmaf(pv.y, wb1.x, ab[rr].x); ab[rr].y = fmaf(pv.y, wb1.y, ab[rr].y);
        ab[rr].z = fmaf(pv.y, wb1.z, ab[rr].z); ab[rr].w = fmaf(pv.y, wb1.w, ab[rr].w);
        ab[rr].x = fmaf(pv.z, wb2.x, ab[rr].x); ab[rr].y = fmaf(pv.z, wb2.y, ab[rr].y);
        ab[rr].z = fmaf(pv.z, wb2.z, ab[rr].z); ab[rr].w = fmaf(pv.z, wb2.w, ab[rr].w);
        ab[rr].x = fmaf(pv.w, wb3.x, ab[rr].x); ab[rr].y = fmaf(pv.w, wb3.y, ab[rr].y);
        ab[rr].z = fmaf(pv.w, wb3.z, ab[rr].z); ab[rr].w = fmaf(pv.w, wb3.w, ab[rr].w);
      }
    }
  }

  // Epilogue: bias + leaky + add + row L2-normalize (shuffle over 32-lane group)
  float4 bg = *(const float4*)(b_gc + 4 * l);
  float4 bb = *(const float4*)(b_bi + 4 * l);

  #pragma unroll
  for (int rr = 0; rr < 4; ++rr) {
    float4 o;
    float x;
    x = ag[rr].x + bg.x; x = (x > 0.f) ? x : LEAKY * x; o.x = x;
    x = ag[rr].y + bg.y; x = (x > 0.f) ? x : LEAKY * x; o.y = x;
    x = ag[rr].z + bg.z; x = (x > 0.f) ? x : LEAKY * x; o.z = x;
    x = ag[rr].w + bg.w; x = (x > 0.f) ? x : LEAKY * x; o.w = x;
    x = ab[rr].x + bb.x; x = (x > 0.f) ? x : LEAKY * x; o.x += x;
    x = ab[rr].y + bb.y; x = (x > 0.f) ? x : LEAKY * x; o.y += x;
    x = ab[rr].z + bb.z; x = (x > 0.f) ? x : LEAKY * x; o.z += x;
    x = ab[rr].w + bb.w; x = (x > 0.f) ? x : LEAKY * x; o.w += x;

    float sq = o.x * o.x + o.y * o.y + o.z * o.z + o.w * o.w;
    #pragma unroll
    for (int off = 16; off > 0; off >>= 1) sq += __shfl_down(sq, off, 32);
    sq = __shfl(sq, 0, 32);
    float inv = rsqrtf(fmaxf(sq, L2EPS));
    o.x *= inv; o.y *= inv; o.z *= inv; o.w *= inv;
    *(float4*)(out + (size_t)(base + r0 + rr) * D + 4 * l) = o;
  }
}

// ===========================================================================
// Fallback (tiny workspace): atomic scatter into out, then transform in place
// ===========================================================================
__global__ __launch_bounds__(256) void scatter_kernel(
    const int*   __restrict__ erow,
    const int*   __restrict__ ecol,
    const float* __restrict__ eval,
    const float* __restrict__ ego,
    float*       __restrict__ side) {
  long long t = (long long)blockIdx.x * blockDim.x + threadIdx.x;
  int e = (int)(t >> 5);
  if (e >= N_EDGES) return;
  int c = (int)(t & 31);
  int r  = erow[e];
  int cl = ecol[e];
  float v = eval[e];
  const float4* src = (const float4*)(ego + (long long)cl * D);
  float4 m = src[c];
  float* dst = side + (long long)r * D + c * 4;
  atomicAdd(dst + 0, v * m.x);
  atomicAdd(dst + 1, v * m.y);
  atomicAdd(dst + 2, v * m.z);
  atomicAdd(dst + 3, v * m.w);
}

// ===========================================================================
extern "C" void kernel_launch(void* const* d_in, const int* in_sizes, int n_in,
                              void* d_out, int out_size, void* d_ws, size_t ws_size,
                              hipStream_t stream) {
  const int*   erow = (const int*)  d_in[0];
  const int*   ecol = (const int*)  d_in[1];
  const float* eval = (const float*)d_in[2];
  const float* ego  = (const float*)d_in[3];
  const float* w_gc = (const float*)d_in[4];
  const float* b_gc = (const float*)d_in[5];
  const float* w_bi = (const float*)d_in[6];
  const float* b_bi = (const float*)d_in[7];
  float* out = (float*)d_out;

  auto align256 = [](size_t x) { return (x + 255) & ~(size_t)255; };
  size_t off_cnt    = 0;
  size_t off_offs   = align256(off_cnt    + (size_t)N_NODES * 4);
  size_t off_cursor = align256(off_offs   + (size_t)(N_NODES + 1) * 4);
  size_t off_bsums  = align256(off_cursor + (size_t)N_NODES * 4);
  size_t off_ev     = align256(off_bsums  + 1024 * 4);
  size_t ws_needed  = off_ev + (size_t)N_EDGES * 8;

  if (ws_size >= ws_needed) {
    char* ws = (char*)d_ws;
    int*  cnt    = (int*) (ws + off_cnt);
    int*  offs   = (int*) (ws + off_offs);
    int*  cursor = (int*) (ws + off_cursor);
    int*  bsums  = (int*) (ws + off_bsums);
    int2* ev     = (int2*)(ws + off_ev);

    // side aliases d_out: spmm writes it; transform reads row-block then
    // overwrites the same rows — no cross-block hazard.
    float* side = out;

    hipMemsetAsync(cnt, 0, (size_t)N_NODES * 4, stream);

    int eg = (N_EDGES + 255) / 256;
    hist_kernel<<<eg, 256, 0, stream>>>(erow, cnt);
    scan_block_sums<<<NB_SCAN, 256, 0, stream>>>(cnt, bsums);
    scan_partials<<<1, 1024, 0, stream>>>(bsums);
    scan_final<<<NB_SCAN, 256, 0, stream>>>(cnt, bsums, offs, cursor);
    bin_kernel<<<eg, 256, 0, stream>>>(erow, ecol, eval, cursor, ev);

    spmm_kernel<<<(N_NODES + 7) / 8, 256, 0, stream>>>(offs, ev, ego, side);
    transform_kernel<<<N_NODES / RPB2, 128, 0, stream>>>(
        side, ego, w_gc, b_gc, w_bi, b_bi, out);
  } else {
    float* side = out;
    hipMemsetAsync(side, 0, (size_t)N_NODES * D * 4, stream);
    long long total = (long long)N_EDGES * 32;
    int grid = (int)((total + 255) / 256);
    scatter_kernel<<<grid, 256, 0, stream>>>(erow, ecol, eval, ego, side);
    transform_kernel<<<N_NODES / RPB2, 128, 0, stream>>>(
        side, ego, w_gc, b_gc, w_bi, b_bi, out);
  }
}

// Round 4
// 571.130 us; speedup vs baseline: 7.8418x; 1.3024x over previous
//
#include <hip/hip_runtime.h>
#include <hip/hip_bf16.h>

constexpr int N_NODES = 150000;
constexpr int N_EDGES = 2400000;
constexpr int D       = 128;
constexpr float LEAKY = 0.2f;
constexpr float L2EPS = 1e-12f;

constexpr int NB_SCAN = (N_NODES + 255) / 256;   // 586 (<1024)

typedef short  short8  __attribute__((ext_vector_type(8)));
typedef short  short4v __attribute__((ext_vector_type(4)));
typedef float  f32x4   __attribute__((ext_vector_type(4)));

static __device__ __forceinline__ short f2bf(float x) {
  __hip_bfloat16 h = __float2bfloat16(x);
  return *reinterpret_cast<short*>(&h);
}

// ===========================================================================
// Counting-sort passes
// ===========================================================================
__global__ __launch_bounds__(256) void hist_kernel(
    const int* __restrict__ erow, int* __restrict__ cnt) {
  int base = blockIdx.x * 1024 + threadIdx.x;
  #pragma unroll
  for (int k = 0; k < 4; ++k) {
    int e = base + k * 256;
    if (e < N_EDGES) atomicAdd(&cnt[erow[e]], 1);
  }
}

__global__ __launch_bounds__(256) void scan_block_sums(
    const int* __restrict__ cnt, int* __restrict__ bsums) {
  __shared__ int s[256];
  int i = blockIdx.x * 256 + threadIdx.x;
  s[threadIdx.x] = (i < N_NODES) ? cnt[i] : 0;
  __syncthreads();
  for (int off = 128; off > 0; off >>= 1) {
    if (threadIdx.x < off) s[threadIdx.x] += s[threadIdx.x + off];
    __syncthreads();
  }
  if (threadIdx.x == 0) bsums[blockIdx.x] = s[0];
}

__global__ __launch_bounds__(1024) void scan_partials(int* __restrict__ bsums) {
  __shared__ int s[1024];
  int v = (threadIdx.x < NB_SCAN) ? bsums[threadIdx.x] : 0;
  s[threadIdx.x] = v;
  __syncthreads();
  for (int off = 1; off < 1024; off <<= 1) {
    int t = (threadIdx.x >= off) ? s[threadIdx.x - off] : 0;
    __syncthreads();
    s[threadIdx.x] += t;
    __syncthreads();
  }
  if (threadIdx.x < NB_SCAN) bsums[threadIdx.x] = s[threadIdx.x] - v;  // exclusive
}

__global__ __launch_bounds__(256) void scan_final(
    const int* __restrict__ cnt, const int* __restrict__ bsums,
    int* __restrict__ offs, int* __restrict__ cursor) {
  __shared__ int s[256];
  int i = blockIdx.x * 256 + threadIdx.x;
  int v = (i < N_NODES) ? cnt[i] : 0;
  s[threadIdx.x] = v;
  __syncthreads();
  for (int off = 1; off < 256; off <<= 1) {
    int t = (threadIdx.x >= off) ? s[threadIdx.x - off] : 0;
    __syncthreads();
    s[threadIdx.x] += t;
    __syncthreads();
  }
  if (i < N_NODES) {
    int excl = s[threadIdx.x] - v + bsums[blockIdx.x];
    offs[i]   = excl;
    cursor[i] = excl;
  }
  if (i == 0) offs[N_NODES] = N_EDGES;
}

__global__ __launch_bounds__(256) void bin_kernel(
    const int*   __restrict__ erow,
    const int*   __restrict__ ecol,
    const float* __restrict__ eval,
    int*         __restrict__ cursor,
    int2*        __restrict__ sorted_ev) {
  int base = blockIdx.x * 1024 + threadIdx.x;
  int e0 = base, e1 = base + 256, e2 = base + 512, e3 = base + 768;
  // 4 independent atomic->store chains per thread for MLP
  int r0 = (e0 < N_EDGES) ? erow[e0] : 0;
  int r1 = (e1 < N_EDGES) ? erow[e1] : 0;
  int r2 = (e2 < N_EDGES) ? erow[e2] : 0;
  int r3 = (e3 < N_EDGES) ? erow[e3] : 0;
  int p0 = (e0 < N_EDGES) ? atomicAdd(&cursor[r0], 1) : 0;
  int p1 = (e1 < N_EDGES) ? atomicAdd(&cursor[r1], 1) : 0;
  int p2 = (e2 < N_EDGES) ? atomicAdd(&cursor[r2], 1) : 0;
  int p3 = (e3 < N_EDGES) ? atomicAdd(&cursor[r3], 1) : 0;
  if (e0 < N_EDGES) sorted_ev[p0] = make_int2(ecol[e0], __float_as_int(eval[e0]));
  if (e1 < N_EDGES) sorted_ev[p1] = make_int2(ecol[e1], __float_as_int(eval[e1]));
  if (e2 < N_EDGES) sorted_ev[p2] = make_int2(ecol[e2], __float_as_int(eval[e2]));
  if (e3 < N_EDGES) sorted_ev[p3] = make_int2(ecol[e3], __float_as_int(eval[e3]));
}

// ===========================================================================
// ego fp32 -> bf16 conversion (halves SpMM gather traffic)
// ===========================================================================
__global__ __launch_bounds__(256) void conv_ego_kernel(
    const float* __restrict__ ego, short* __restrict__ ebf) {
  int i = blockIdx.x * 256 + threadIdx.x;      // float4 slot
  constexpr int TOTAL = N_NODES * D / 4;       // 4.8M
  if (i < TOTAL) {
    float4 v = ((const float4*)ego)[i];
    short4v p;
    p[0] = f2bf(v.x); p[1] = f2bf(v.y); p[2] = f2bf(v.z); p[3] = f2bf(v.w);
    ((short4v*)ebf)[i] = p;
  }
}

// ===========================================================================
// Weight prepack: w[k][n] fp32 -> wT[n][k] bf16 (contiguous B-fragments)
// ===========================================================================
__global__ __launch_bounds__(128) void prep_weights_kernel(
    const float* __restrict__ wg, const float* __restrict__ wb,
    short* __restrict__ wtg, short* __restrict__ wtb) {
  int n = blockIdx.x;      // 128
  int k = threadIdx.x;     // 128
  wtg[n * D + k] = f2bf(wg[k * D + n]);
  wtb[n * D + k] = f2bf(wb[k * D + n]);
}

// ===========================================================================
// SpMM (bf16 ego): one row per 16-lane group, 16B gathers, unroll 4.
// Block 256 = 16 rows; grid = 150000/16 = 9375 exact.
// ===========================================================================
__global__ __launch_bounds__(256) void spmm_bf16_kernel(
    const int*   __restrict__ offs,
    const int2*  __restrict__ ev,
    const short* __restrict__ ebf,
    float*       __restrict__ side) {
  const int t = threadIdx.x;
  const int g = t >> 4;
  const int l = t & 15;
  const int row = blockIdx.x * 16 + g;

  const int s0 = offs[row], s1 = offs[row + 1];
  float a0 = 0.f, a1 = 0.f, a2 = 0.f, a3 = 0.f;
  float a4 = 0.f, a5 = 0.f, a6 = 0.f, a7 = 0.f;

  auto accum = [&](int2 e) {
    uint4 u = *(const uint4*)(ebf + (size_t)e.x * D + l * 8);
    float v = __int_as_float(e.y);
    a0 = fmaf(v, __uint_as_float(u.x << 16), a0);
    a1 = fmaf(v, __uint_as_float(u.x & 0xffff0000u), a1);
    a2 = fmaf(v, __uint_as_float(u.y << 16), a2);
    a3 = fmaf(v, __uint_as_float(u.y & 0xffff0000u), a3);
    a4 = fmaf(v, __uint_as_float(u.z << 16), a4);
    a5 = fmaf(v, __uint_as_float(u.z & 0xffff0000u), a5);
    a6 = fmaf(v, __uint_as_float(u.w << 16), a6);
    a7 = fmaf(v, __uint_as_float(u.w & 0xffff0000u), a7);
  };

  int i = s0;
  const int n4 = s0 + ((s1 - s0) & ~3);
  for (; i < n4; i += 4) {
    int2 e0 = ev[i], e1 = ev[i + 1], e2 = ev[i + 2], e3 = ev[i + 3];
    accum(e0); accum(e1); accum(e2); accum(e3);
  }
  for (; i < s1; ++i) accum(ev[i]);

  float* dst = side + (size_t)row * D + l * 8;
  *(float4*)(dst)     = make_float4(a0, a1, a2, a3);
  *(float4*)(dst + 4) = make_float4(a4, a5, a6, a7);
}

// fp32-ego fallback SpMM (mid tier)
__global__ __launch_bounds__(256) void spmm_kernel(
    const int*  __restrict__ offs,
    const int2* __restrict__ ev,
    const float* __restrict__ ego,
    float*       __restrict__ side) {
  const int t = threadIdx.x;
  const int g = t >> 5;
  const int l = t & 31;
  const int row = blockIdx.x * 8 + g;
  if (row >= N_NODES) return;
  const int s0 = offs[row], s1 = offs[row + 1];
  float ax = 0.f, ay = 0.f, az = 0.f, aw = 0.f;
  int i = s0;
  const int n4 = s0 + ((s1 - s0) & ~3);
  for (; i < n4; i += 4) {
    int2 e0 = ev[i], e1 = ev[i + 1], e2 = ev[i + 2], e3 = ev[i + 3];
    float4 g0 = *(const float4*)(ego + (size_t)e0.x * D + 4 * l);
    float4 g1 = *(const float4*)(ego + (size_t)e1.x * D + 4 * l);
    float4 g2 = *(const float4*)(ego + (size_t)e2.x * D + 4 * l);
    float4 g3 = *(const float4*)(ego + (size_t)e3.x * D + 4 * l);
    float v0 = __int_as_float(e0.y), v1 = __int_as_float(e1.y);
    float v2 = __int_as_float(e2.y), v3 = __int_as_float(e3.y);
    ax = fmaf(v0, g0.x, ax); ay = fmaf(v0, g0.y, ay);
    az = fmaf(v0, g0.z, az); aw = fmaf(v0, g0.w, aw);
    ax = fmaf(v1, g1.x, ax); ay = fmaf(v1, g1.y, ay);
    az = fmaf(v1, g1.z, az); aw = fmaf(v1, g1.w, aw);
    ax = fmaf(v2, g2.x, ax); ay = fmaf(v2, g2.y, ay);
    az = fmaf(v2, g2.z, az); aw = fmaf(v2, g2.w, aw);
    ax = fmaf(v3, g3.x, ax); ay = fmaf(v3, g3.y, ay);
    az = fmaf(v3, g3.z, az); aw = fmaf(v3, g3.w, aw);
  }
  for (; i < s1; ++i) {
    int2 e = ev[i];
    float4 gg = *(const float4*)(ego + (size_t)e.x * D + 4 * l);
    float v = __int_as_float(e.y);
    ax = fmaf(v, gg.x, ax); ay = fmaf(v, gg.y, ay);
    az = fmaf(v, gg.z, az); aw = fmaf(v, gg.w, aw);
  }
  *(float4*)(side + (size_t)row * D + 4 * l) = make_float4(ax, ay, az, aw);
}

// ===========================================================================
// MFMA transform: dual bf16 GEMM + bias + leaky + add + L2-normalize.
// Block = 256 (4 waves), 16 rows per block; wave w owns cols [32w, 32w+32).
// A-frags (side, ego*side) bf16 in LDS; B-frags from prepacked wT (global).
// side may alias out (block reads exactly the rows it later writes).
// ===========================================================================
__global__ __launch_bounds__(256) void transform_mfma_kernel(
    const float* __restrict__ side,
    const float* __restrict__ ego,
    const short* __restrict__ wtg,
    const short* __restrict__ wtb,
    const float* __restrict__ b_gc,
    const float* __restrict__ b_bi,
    float*       __restrict__ out) {
  __shared__ short sA[16][136];   // side  (bf16), +8 pad: 2-way banks = free
  __shared__ short sP[16][136];   // ego*side (bf16)
  __shared__ float sO[16][132];   // fused pre-norm output
  __shared__ float sInv[16];

  const int t    = threadIdx.x;
  const int w    = t >> 6;
  const int l    = t & 63;
  const int base = blockIdx.x * 16;

  // Stage 16 rows of side / prod as bf16
  #pragma unroll
  for (int k = 0; k < 2; ++k) {
    int f  = k * 256 + t;          // 512 float4 slots
    int r  = f >> 5;
    int c4 = (f & 31) * 4;
    float4 sv = *(const float4*)(side + (size_t)(base + r) * D + c4);
    float4 ev = *(const float4*)(ego  + (size_t)(base + r) * D + c4);
    short4v pa, pp;
    pa[0] = f2bf(sv.x); pa[1] = f2bf(sv.y); pa[2] = f2bf(sv.z); pa[3] = f2bf(sv.w);
    pp[0] = f2bf(sv.x * ev.x); pp[1] = f2bf(sv.y * ev.y);
    pp[2] = f2bf(sv.z * ev.z); pp[3] = f2bf(sv.w * ev.w);
    *(short4v*)&sA[r][c4] = pa;
    *(short4v*)&sP[r][c4] = pp;
  }
  __syncthreads();

  f32x4 accg[2] = {{0.f, 0.f, 0.f, 0.f}, {0.f, 0.f, 0.f, 0.f}};
  f32x4 accb[2] = {{0.f, 0.f, 0.f, 0.f}, {0.f, 0.f, 0.f, 0.f}};

  const int arow = l & 15;            // A row / B col-within-tile
  const int koff = (l >> 4) * 8;      // k sub-offset per quad
  const int nb   = w * 32;

  #pragma unroll
  for (int ks = 0; ks < 4; ++ks) {
    const int k0 = ks * 32 + koff;
    short8 a_s = *(const short8*)&sA[arow][k0];
    short8 a_p = *(const short8*)&sP[arow][k0];
    #pragma unroll
    for (int ct = 0; ct < 2; ++ct) {
      const int n = nb + ct * 16 + arow;
      short8 bgf = *(const short8*)(wtg + (size_t)n * D + k0);
      short8 bbf = *(const short8*)(wtb + (size_t)n * D + k0);
      accg[ct] = __builtin_amdgcn_mfma_f32_16x16x32_bf16(a_s, bgf, accg[ct], 0, 0, 0);
      accb[ct] = __builtin_amdgcn_mfma_f32_16x16x32_bf16(a_p, bbf, accb[ct], 0, 0, 0);
    }
  }

  // Epilogue: bias + leaky + add -> sO   (C/D: row=(l>>4)*4+j, col=lane&15)
  #pragma unroll
  for (int ct = 0; ct < 2; ++ct) {
    const int col = nb + ct * 16 + arow;
    const float bg = b_gc[col];
    const float bb = b_bi[col];
    #pragma unroll
    for (int j = 0; j < 4; ++j) {
      const int r = (l >> 4) * 4 + j;
      float x1 = accg[ct][j] + bg; x1 = (x1 > 0.f) ? x1 : LEAKY * x1;
      float x2 = accb[ct][j] + bb; x2 = (x2 > 0.f) ? x2 : LEAKY * x2;
      sO[r][col] = x1 + x2;
    }
  }
  __syncthreads();

  // Row L2 norm: 16 threads per row, 8 elements each
  {
    const int r = t >> 4, c16 = t & 15;
    float sum = 0.f;
    #pragma unroll
    for (int i = 0; i < 8; ++i) {
      float v = sO[r][c16 * 8 + i];
      sum = fmaf(v, v, sum);
    }
    #pragma unroll
    for (int off = 8; off > 0; off >>= 1) sum += __shfl_down(sum, off, 16);
    if (c16 == 0) sInv[r] = rsqrtf(fmaxf(sum, L2EPS));
  }
  __syncthreads();

  #pragma unroll
  for (int k = 0; k < 2; ++k) {
    int f  = k * 256 + t;
    int r  = f >> 5;
    int c4 = (f & 31) * 4;
    float inv = sInv[r];
    float4 v = *(const float4*)&sO[r][c4];
    v.x *= inv; v.y *= inv; v.z *= inv; v.w *= inv;
    *(float4*)(out + (size_t)(base + r) * D + c4) = v;
  }
}

// ===========================================================================
// Tiny-workspace fallback: atomic scatter + fp32 transform (rarely used)
// ===========================================================================
__global__ __launch_bounds__(256) void scatter_kernel(
    const int*   __restrict__ erow,
    const int*   __restrict__ ecol,
    const float* __restrict__ eval,
    const float* __restrict__ ego,
    float*       __restrict__ side) {
  long long t = (long long)blockIdx.x * blockDim.x + threadIdx.x;
  int e = (int)(t >> 5);
  if (e >= N_EDGES) return;
  int c = (int)(t & 31);
  int r  = erow[e];
  int cl = ecol[e];
  float v = eval[e];
  const float4* src = (const float4*)(ego + (long long)cl * D);
  float4 m = src[c];
  float* dst = side + (long long)r * D + c * 4;
  atomicAdd(dst + 0, v * m.x);
  atomicAdd(dst + 1, v * m.y);
  atomicAdd(dst + 2, v * m.z);
  atomicAdd(dst + 3, v * m.w);
}

__global__ __launch_bounds__(128) void transform_f32_kernel(
    const float* __restrict__ side,
    const float* __restrict__ ego,
    const float* __restrict__ w_gc,
    const float* __restrict__ b_gc,
    const float* __restrict__ w_bi,
    const float* __restrict__ b_bi,
    float*       __restrict__ out) {
  constexpr int RPB = 16;
  __shared__ float s_side[RPB][D];
  __shared__ float s_prod[RPB][D];
  __shared__ float s_part[RPB][2];
  const int j    = threadIdx.x;
  const int base = blockIdx.x * RPB;
  #pragma unroll
  for (int r = 0; r < RPB; ++r) {
    int node = base + r;
    float s = 0.f, e = 0.f;
    if (node < N_NODES) {
      s = side[(long long)node * D + j];
      e = ego [(long long)node * D + j];
    }
    s_side[r][j] = s;
    s_prod[r][j] = e * s;
  }
  __syncthreads();
  float acc_gc[RPB], acc_bi[RPB];
  #pragma unroll
  for (int r = 0; r < RPB; ++r) { acc_gc[r] = 0.f; acc_bi[r] = 0.f; }
  for (int k = 0; k < D; ++k) {
    float wg = w_gc[k * D + j];
    float wb = w_bi[k * D + j];
    #pragma unroll
    for (int r = 0; r < RPB; ++r) {
      acc_gc[r] = fmaf(s_side[r][k], wg, acc_gc[r]);
      acc_bi[r] = fmaf(s_prod[r][k], wb, acc_bi[r]);
    }
  }
  const float bg = b_gc[j];
  const float bb = b_bi[j];
  #pragma unroll
  for (int r = 0; r < RPB; ++r) {
    float x1 = acc_gc[r] + bg; x1 = (x1 > 0.f) ? x1 : LEAKY * x1;
    float x2 = acc_bi[r] + bb; x2 = (x2 > 0.f) ? x2 : LEAKY * x2;
    acc_gc[r] = x1 + x2;
  }
  const int lane = j & 63;
  const int wv   = j >> 6;
  #pragma unroll
  for (int r = 0; r < RPB; ++r) {
    float sq = acc_gc[r] * acc_gc[r];
    #pragma unroll
    for (int off = 32; off > 0; off >>= 1) sq += __shfl_down(sq, off, 64);
    if (lane == 0) s_part[r][wv] = sq;
  }
  __syncthreads();
  #pragma unroll
  for (int r = 0; r < RPB; ++r) {
    int node = base + r;
    if (node < N_NODES) {
      float tot = s_part[r][0] + s_part[r][1];
      float inv = rsqrtf(fmaxf(tot, L2EPS));
      out[(long long)node * D + j] = acc_gc[r] * inv;
    }
  }
}

// ===========================================================================
extern "C" void kernel_launch(void* const* d_in, const int* in_sizes, int n_in,
                              void* d_out, int out_size, void* d_ws, size_t ws_size,
                              hipStream_t stream) {
  const int*   erow = (const int*)  d_in[0];
  const int*   ecol = (const int*)  d_in[1];
  const float* eval = (const float*)d_in[2];
  const float* ego  = (const float*)d_in[3];
  const float* w_gc = (const float*)d_in[4];
  const float* b_gc = (const float*)d_in[5];
  const float* w_bi = (const float*)d_in[6];
  const float* b_bi = (const float*)d_in[7];
  float* out = (float*)d_out;

  auto align256 = [](size_t x) { return (x + 255) & ~(size_t)255; };
  size_t off_cnt    = 0;
  size_t off_offs   = align256(off_cnt    + (size_t)N_NODES * 4);
  size_t off_cursor = align256(off_offs   + (size_t)(N_NODES + 1) * 4);
  size_t off_bsums  = align256(off_cursor + (size_t)N_NODES * 4);
  size_t off_wtg    = align256(off_bsums  + 1024 * 4);
  size_t off_wtb    = align256(off_wtg    + (size_t)D * D * 2);
  size_t off_ev     = align256(off_wtb    + (size_t)D * D * 2);
  size_t off_ebf    = align256(off_ev     + (size_t)N_EDGES * 8);
  size_t ws_mid     = off_ebf;                                   // ~21.2 MB
  size_t ws_full    = off_ebf + (size_t)N_NODES * D * 2;         // ~59.6 MB

  if (ws_size >= ws_mid) {
    char* ws = (char*)d_ws;
    int*   cnt    = (int*)  (ws + off_cnt);
    int*   offs   = (int*)  (ws + off_offs);
    int*   cursor = (int*)  (ws + off_cursor);
    int*   bsums  = (int*)  (ws + off_bsums);
    short* wtg    = (short*)(ws + off_wtg);
    short* wtb    = (short*)(ws + off_wtb);
    int2*  ev     = (int2*) (ws + off_ev);
    short* ebf    = (short*)(ws + off_ebf);

    float* side = out;   // alias: spmm writes all rows; transform is row-local

    hipMemsetAsync(cnt, 0, (size_t)N_NODES * 4, stream);

    int eg4 = (N_EDGES + 1023) / 1024;
    hist_kernel<<<eg4, 256, 0, stream>>>(erow, cnt);
    scan_block_sums<<<NB_SCAN, 256, 0, stream>>>(cnt, bsums);
    scan_partials<<<1, 1024, 0, stream>>>(bsums);
    scan_final<<<NB_SCAN, 256, 0, stream>>>(cnt, bsums, offs, cursor);
    bin_kernel<<<eg4, 256, 0, stream>>>(erow, ecol, eval, cursor, ev);
    prep_weights_kernel<<<D, D, 0, stream>>>(w_gc, w_bi, wtg, wtb);

    if (ws_size >= ws_full) {
      conv_ego_kernel<<<(N_NODES * D / 4 + 255) / 256, 256, 0, stream>>>(ego, ebf);
      spmm_bf16_kernel<<<N_NODES / 16, 256, 0, stream>>>(offs, ev, ebf, side);
    } else {
      spmm_kernel<<<(N_NODES + 7) / 8, 256, 0, stream>>>(offs, ev, ego, side);
    }
    transform_mfma_kernel<<<N_NODES / 16, 256, 0, stream>>>(
        side, ego, wtg, wtb, b_gc, b_bi, out);
  } else {
    float* side = out;
    hipMemsetAsync(side, 0, (size_t)N_NODES * D * 4, stream);
    long long total = (long long)N_EDGES * 32;
    int grid = (int)((total + 255) / 256);
    scatter_kernel<<<grid, 256, 0, stream>>>(erow, ecol, eval, ego, side);
    transform_f32_kernel<<<N_NODES / 16, 128, 0, stream>>>(
        side, ego, w_gc, b_gc, w_bi, b_bi, out);
  }
}

// Round 5
// 509.939 us; speedup vs baseline: 8.7828x; 1.1200x over previous
//
#include <hip/hip_runtime.h>
#include <hip/hip_bf16.h>

constexpr int N_NODES = 150000;
constexpr int N_EDGES = 2400000;
constexpr int D       = 128;
constexpr float LEAKY = 0.2f;
constexpr float L2EPS = 1e-12f;

constexpr int NB_SCAN = (N_NODES + 255) / 256;   // 586 (<1024)

// Bucket sort params
constexpr int RB_LOG = 9;                               // 512 rows / bucket
constexpr int RB     = 1 << RB_LOG;
constexpr int NBK    = (N_NODES + RB - 1) >> RB_LOG;    // 293
constexpr int EPT_A  = 32;                              // edges / thread, phase A
constexpr int EPB_A  = 256 * EPT_A;                     // 8192 edges / block

typedef short  short8  __attribute__((ext_vector_type(8)));
typedef short  short4v __attribute__((ext_vector_type(4)));
typedef float  f32x4   __attribute__((ext_vector_type(4)));

static __device__ __forceinline__ short f2bf(float x) {
  __hip_bfloat16 h = __float2bfloat16(x);
  return *reinterpret_cast<short*>(&h);
}

// ===========================================================================
// Histogram + scans (per-row counts -> offs)
// ===========================================================================
__global__ __launch_bounds__(256) void hist_kernel(
    const int* __restrict__ erow, int* __restrict__ cnt) {
  int base = blockIdx.x * 2048 + threadIdx.x;
  #pragma unroll
  for (int k = 0; k < 8; ++k) {
    int e = base + k * 256;
    if (e < N_EDGES) atomicAdd(&cnt[erow[e]], 1);
  }
}

__global__ __launch_bounds__(256) void scan_block_sums(
    const int* __restrict__ cnt, int* __restrict__ bsums) {
  __shared__ int s[256];
  int i = blockIdx.x * 256 + threadIdx.x;
  s[threadIdx.x] = (i < N_NODES) ? cnt[i] : 0;
  __syncthreads();
  for (int off = 128; off > 0; off >>= 1) {
    if (threadIdx.x < off) s[threadIdx.x] += s[threadIdx.x + off];
    __syncthreads();
  }
  if (threadIdx.x == 0) bsums[blockIdx.x] = s[0];
}

__global__ __launch_bounds__(1024) void scan_partials(int* __restrict__ bsums) {
  __shared__ int s[1024];
  int v = (threadIdx.x < NB_SCAN) ? bsums[threadIdx.x] : 0;
  s[threadIdx.x] = v;
  __syncthreads();
  for (int off = 1; off < 1024; off <<= 1) {
    int t = (threadIdx.x >= off) ? s[threadIdx.x - off] : 0;
    __syncthreads();
    s[threadIdx.x] += t;
    __syncthreads();
  }
  if (threadIdx.x < NB_SCAN) bsums[threadIdx.x] = s[threadIdx.x] - v;  // exclusive
}

__global__ __launch_bounds__(256) void scan_final(
    const int* __restrict__ cnt, const int* __restrict__ bsums,
    int* __restrict__ offs, int* __restrict__ cursor,
    int* __restrict__ bcur) {
  __shared__ int s[256];
  int i = blockIdx.x * 256 + threadIdx.x;
  int v = (i < N_NODES) ? cnt[i] : 0;
  s[threadIdx.x] = v;
  __syncthreads();
  for (int off = 1; off < 256; off <<= 1) {
    int t = (threadIdx.x >= off) ? s[threadIdx.x - off] : 0;
    __syncthreads();
    s[threadIdx.x] += t;
    __syncthreads();
  }
  if (i < N_NODES) {
    int excl = s[threadIdx.x] - v + bsums[blockIdx.x];
    offs[i]   = excl;
    cursor[i] = excl;
    if ((i & (RB - 1)) == 0) bcur[i >> RB_LOG] = excl;  // bucket base
  }
  if (i == 0) offs[N_NODES] = N_EDGES;
}

// ===========================================================================
// Phase A: bucket scatter with coalesced run-writes into stage.
// stage layout == final layout at bucket granularity (base = offs[512b]).
// Packs rlocal (9 bits) into bits 18..26 of the col word.
// ===========================================================================
__global__ __launch_bounds__(256) void bucket_scatter_kernel(
    const int*   __restrict__ erow,
    const int*   __restrict__ ecol,
    const float* __restrict__ eval,
    int*         __restrict__ bcur,
    int2*        __restrict__ stage) {
  __shared__ int h[NBK];
  __shared__ int basea[NBK];
  const int t = threadIdx.x;
  const long long e0 = (long long)blockIdx.x * EPB_A;

  for (int i = t; i < NBK; i += 256) h[i] = 0;
  __syncthreads();

  int rows[EPT_A];
  #pragma unroll
  for (int k = 0; k < EPT_A; ++k) {
    long long e = e0 + k * 256 + t;
    int r = -1;
    if (e < N_EDGES) { r = erow[e]; atomicAdd(&h[r >> RB_LOG], 1); }
    rows[k] = r;
  }
  __syncthreads();

  for (int b = t; b < NBK; b += 256) {
    int c = h[b];
    basea[b] = c ? atomicAdd(&bcur[b], c) : 0;
    h[b] = 0;
  }
  __syncthreads();

  #pragma unroll
  for (int k = 0; k < EPT_A; ++k) {
    int r = rows[k];
    if (r >= 0) {
      long long e = e0 + k * 256 + t;
      int bkt  = r >> RB_LOG;
      int rank = atomicAdd(&h[bkt], 1);
      int pos  = basea[bkt] + rank;
      int pack = ecol[e] | ((r & (RB - 1)) << 18);
      stage[pos] = make_int2(pack, __float_as_int(eval[e]));
    }
  }
}

// ===========================================================================
// Phase B: per-bucket in-window permute to exact row order.
// One block per bucket; writes land in a ~65KB window (one CU -> one XCD L2).
// ===========================================================================
__global__ __launch_bounds__(256) void bucket_permute_kernel(
    const int*  __restrict__ offs,
    const int2* __restrict__ stage,
    int2*       __restrict__ ev) {
  __shared__ int cur[RB];
  const int t    = threadIdx.x;
  const int row0 = blockIdx.x << RB_LOG;

  for (int i = t; i < RB; i += 256) {
    int r = row0 + i;
    cur[i] = (r < N_NODES) ? offs[r] : N_EDGES;
  }
  __syncthreads();

  const int w0 = offs[row0];
  const int w1 = offs[min(row0 + RB, N_NODES)];
  for (int i = w0 + t; i < w1; i += 256) {
    int2 e = stage[i];
    int rl  = (e.x >> 18) & (RB - 1);
    int pos = atomicAdd(&cur[rl], 1);
    ev[pos] = make_int2(e.x & 0x3FFFF, e.y);
  }
}

// ===========================================================================
// Old single-pass bin (mid-tier fallback)
// ===========================================================================
__global__ __launch_bounds__(256) void bin_kernel(
    const int*   __restrict__ erow,
    const int*   __restrict__ ecol,
    const float* __restrict__ eval,
    int*         __restrict__ cursor,
    int2*        __restrict__ sorted_ev) {
  int base = blockIdx.x * 1024 + threadIdx.x;
  int e0 = base, e1 = base + 256, e2 = base + 512, e3 = base + 768;
  int r0 = (e0 < N_EDGES) ? erow[e0] : 0;
  int r1 = (e1 < N_EDGES) ? erow[e1] : 0;
  int r2 = (e2 < N_EDGES) ? erow[e2] : 0;
  int r3 = (e3 < N_EDGES) ? erow[e3] : 0;
  int p0 = (e0 < N_EDGES) ? atomicAdd(&cursor[r0], 1) : 0;
  int p1 = (e1 < N_EDGES) ? atomicAdd(&cursor[r1], 1) : 0;
  int p2 = (e2 < N_EDGES) ? atomicAdd(&cursor[r2], 1) : 0;
  int p3 = (e3 < N_EDGES) ? atomicAdd(&cursor[r3], 1) : 0;
  if (e0 < N_EDGES) sorted_ev[p0] = make_int2(ecol[e0], __float_as_int(eval[e0]));
  if (e1 < N_EDGES) sorted_ev[p1] = make_int2(ecol[e1], __float_as_int(eval[e1]));
  if (e2 < N_EDGES) sorted_ev[p2] = make_int2(ecol[e2], __float_as_int(eval[e2]));
  if (e3 < N_EDGES) sorted_ev[p3] = make_int2(ecol[e3], __float_as_int(eval[e3]));
}

// ===========================================================================
// ego fp32 -> bf16 conversion
// ===========================================================================
__global__ __launch_bounds__(256) void conv_ego_kernel(
    const float* __restrict__ ego, short* __restrict__ ebf) {
  int i = blockIdx.x * 256 + threadIdx.x;      // float4 slot
  constexpr int TOTAL = N_NODES * D / 4;
  if (i < TOTAL) {
    float4 v = ((const float4*)ego)[i];
    short4v p;
    p[0] = f2bf(v.x); p[1] = f2bf(v.y); p[2] = f2bf(v.z); p[3] = f2bf(v.w);
    ((short4v*)ebf)[i] = p;
  }
}

// ===========================================================================
// Weight prepack: w[k][n] fp32 -> wT[n][k] bf16
// ===========================================================================
__global__ __launch_bounds__(128) void prep_weights_kernel(
    const float* __restrict__ wg, const float* __restrict__ wb,
    short* __restrict__ wtg, short* __restrict__ wtb) {
  int n = blockIdx.x;
  int k = threadIdx.x;
  wtg[n * D + k] = f2bf(wg[k * D + n]);
  wtb[n * D + k] = f2bf(wb[k * D + n]);
}

// ===========================================================================
// SpMM (bf16 ego): one row per 16-lane group, 16B gathers, unroll 4.
// ===========================================================================
__global__ __launch_bounds__(256) void spmm_bf16_kernel(
    const int*   __restrict__ offs,
    const int2*  __restrict__ ev,
    const short* __restrict__ ebf,
    float*       __restrict__ side) {
  const int t = threadIdx.x;
  const int g = t >> 4;
  const int l = t & 15;
  const int row = blockIdx.x * 16 + g;

  const int s0 = offs[row], s1 = offs[row + 1];
  float a0 = 0.f, a1 = 0.f, a2 = 0.f, a3 = 0.f;
  float a4 = 0.f, a5 = 0.f, a6 = 0.f, a7 = 0.f;

  auto accum = [&](int2 e) {
    uint4 u = *(const uint4*)(ebf + (size_t)e.x * D + l * 8);
    float v = __int_as_float(e.y);
    a0 = fmaf(v, __uint_as_float(u.x << 16), a0);
    a1 = fmaf(v, __uint_as_float(u.x & 0xffff0000u), a1);
    a2 = fmaf(v, __uint_as_float(u.y << 16), a2);
    a3 = fmaf(v, __uint_as_float(u.y & 0xffff0000u), a3);
    a4 = fmaf(v, __uint_as_float(u.z << 16), a4);
    a5 = fmaf(v, __uint_as_float(u.z & 0xffff0000u), a5);
    a6 = fmaf(v, __uint_as_float(u.w << 16), a6);
    a7 = fmaf(v, __uint_as_float(u.w & 0xffff0000u), a7);
  };

  int i = s0;
  const int n4 = s0 + ((s1 - s0) & ~3);
  for (; i < n4; i += 4) {
    int2 e0 = ev[i], e1 = ev[i + 1], e2 = ev[i + 2], e3 = ev[i + 3];
    accum(e0); accum(e1); accum(e2); accum(e3);
  }
  for (; i < s1; ++i) accum(ev[i]);

  float* dst = side + (size_t)row * D + l * 8;
  *(float4*)(dst)     = make_float4(a0, a1, a2, a3);
  *(float4*)(dst + 4) = make_float4(a4, a5, a6, a7);
}

// fp32-ego SpMM (sort/mid tiers)
__global__ __launch_bounds__(256) void spmm_kernel(
    const int*  __restrict__ offs,
    const int2* __restrict__ ev,
    const float* __restrict__ ego,
    float*       __restrict__ side) {
  const int t = threadIdx.x;
  const int g = t >> 5;
  const int l = t & 31;
  const int row = blockIdx.x * 8 + g;
  if (row >= N_NODES) return;
  const int s0 = offs[row], s1 = offs[row + 1];
  float ax = 0.f, ay = 0.f, az = 0.f, aw = 0.f;
  int i = s0;
  const int n4 = s0 + ((s1 - s0) & ~3);
  for (; i < n4; i += 4) {
    int2 e0 = ev[i], e1 = ev[i + 1], e2 = ev[i + 2], e3 = ev[i + 3];
    float4 g0 = *(const float4*)(ego + (size_t)e0.x * D + 4 * l);
    float4 g1 = *(const float4*)(ego + (size_t)e1.x * D + 4 * l);
    float4 g2 = *(const float4*)(ego + (size_t)e2.x * D + 4 * l);
    float4 g3 = *(const float4*)(ego + (size_t)e3.x * D + 4 * l);
    float v0 = __int_as_float(e0.y), v1 = __int_as_float(e1.y);
    float v2 = __int_as_float(e2.y), v3 = __int_as_float(e3.y);
    ax = fmaf(v0, g0.x, ax); ay = fmaf(v0, g0.y, ay);
    az = fmaf(v0, g0.z, az); aw = fmaf(v0, g0.w, aw);
    ax = fmaf(v1, g1.x, ax); ay = fmaf(v1, g1.y, ay);
    az = fmaf(v1, g1.z, az); aw = fmaf(v1, g1.w, aw);
    ax = fmaf(v2, g2.x, ax); ay = fmaf(v2, g2.y, ay);
    az = fmaf(v2, g2.z, az); aw = fmaf(v2, g2.w, aw);
    ax = fmaf(v3, g3.x, ax); ay = fmaf(v3, g3.y, ay);
    az = fmaf(v3, g3.z, az); aw = fmaf(v3, g3.w, aw);
  }
  for (; i < s1; ++i) {
    int2 e = ev[i];
    float4 gg = *(const float4*)(ego + (size_t)e.x * D + 4 * l);
    float v = __int_as_float(e.y);
    ax = fmaf(v, gg.x, ax); ay = fmaf(v, gg.y, ay);
    az = fmaf(v, gg.z, az); aw = fmaf(v, gg.w, aw);
  }
  *(float4*)(side + (size_t)row * D + 4 * l) = make_float4(ax, ay, az, aw);
}

// ===========================================================================
// MFMA transform (unchanged from round 4)
// ===========================================================================
__global__ __launch_bounds__(256) void transform_mfma_kernel(
    const float* __restrict__ side,
    const float* __restrict__ ego,
    const short* __restrict__ wtg,
    const short* __restrict__ wtb,
    const float* __restrict__ b_gc,
    const float* __restrict__ b_bi,
    float*       __restrict__ out) {
  __shared__ short sA[16][136];
  __shared__ short sP[16][136];
  __shared__ float sO[16][132];
  __shared__ float sInv[16];

  const int t    = threadIdx.x;
  const int w    = t >> 6;
  const int l    = t & 63;
  const int base = blockIdx.x * 16;

  #pragma unroll
  for (int k = 0; k < 2; ++k) {
    int f  = k * 256 + t;
    int r  = f >> 5;
    int c4 = (f & 31) * 4;
    float4 sv = *(const float4*)(side + (size_t)(base + r) * D + c4);
    float4 ev = *(const float4*)(ego  + (size_t)(base + r) * D + c4);
    short4v pa, pp;
    pa[0] = f2bf(sv.x); pa[1] = f2bf(sv.y); pa[2] = f2bf(sv.z); pa[3] = f2bf(sv.w);
    pp[0] = f2bf(sv.x * ev.x); pp[1] = f2bf(sv.y * ev.y);
    pp[2] = f2bf(sv.z * ev.z); pp[3] = f2bf(sv.w * ev.w);
    *(short4v*)&sA[r][c4] = pa;
    *(short4v*)&sP[r][c4] = pp;
  }
  __syncthreads();

  f32x4 accg[2] = {{0.f, 0.f, 0.f, 0.f}, {0.f, 0.f, 0.f, 0.f}};
  f32x4 accb[2] = {{0.f, 0.f, 0.f, 0.f}, {0.f, 0.f, 0.f, 0.f}};

  const int arow = l & 15;
  const int koff = (l >> 4) * 8;
  const int nb   = w * 32;

  #pragma unroll
  for (int ks = 0; ks < 4; ++ks) {
    const int k0 = ks * 32 + koff;
    short8 a_s = *(const short8*)&sA[arow][k0];
    short8 a_p = *(const short8*)&sP[arow][k0];
    #pragma unroll
    for (int ct = 0; ct < 2; ++ct) {
      const int n = nb + ct * 16 + arow;
      short8 bgf = *(const short8*)(wtg + (size_t)n * D + k0);
      short8 bbf = *(const short8*)(wtb + (size_t)n * D + k0);
      accg[ct] = __builtin_amdgcn_mfma_f32_16x16x32_bf16(a_s, bgf, accg[ct], 0, 0, 0);
      accb[ct] = __builtin_amdgcn_mfma_f32_16x16x32_bf16(a_p, bbf, accb[ct], 0, 0, 0);
    }
  }

  #pragma unroll
  for (int ct = 0; ct < 2; ++ct) {
    const int col = nb + ct * 16 + arow;
    const float bg = b_gc[col];
    const float bb = b_bi[col];
    #pragma unroll
    for (int j = 0; j < 4; ++j) {
      const int r = (l >> 4) * 4 + j;
      float x1 = accg[ct][j] + bg; x1 = (x1 > 0.f) ? x1 : LEAKY * x1;
      float x2 = accb[ct][j] + bb; x2 = (x2 > 0.f) ? x2 : LEAKY * x2;
      sO[r][col] = x1 + x2;
    }
  }
  __syncthreads();

  {
    const int r = t >> 4, c16 = t & 15;
    float sum = 0.f;
    #pragma unroll
    for (int i = 0; i < 8; ++i) {
      float v = sO[r][c16 * 8 + i];
      sum = fmaf(v, v, sum);
    }
    #pragma unroll
    for (int off = 8; off > 0; off >>= 1) sum += __shfl_down(sum, off, 16);
    if (c16 == 0) sInv[r] = rsqrtf(fmaxf(sum, L2EPS));
  }
  __syncthreads();

  #pragma unroll
  for (int k = 0; k < 2; ++k) {
    int f  = k * 256 + t;
    int r  = f >> 5;
    int c4 = (f & 31) * 4;
    float inv = sInv[r];
    float4 v = *(const float4*)&sO[r][c4];
    v.x *= inv; v.y *= inv; v.z *= inv; v.w *= inv;
    *(float4*)(out + (size_t)(base + r) * D + c4) = v;
  }
}

// ===========================================================================
// Tiny-workspace fallback
// ===========================================================================
__global__ __launch_bounds__(256) void scatter_kernel(
    const int*   __restrict__ erow,
    const int*   __restrict__ ecol,
    const float* __restrict__ eval,
    const float* __restrict__ ego,
    float*       __restrict__ side) {
  long long t = (long long)blockIdx.x * blockDim.x + threadIdx.x;
  int e = (int)(t >> 5);
  if (e >= N_EDGES) return;
  int c = (int)(t & 31);
  int r  = erow[e];
  int cl = ecol[e];
  float v = eval[e];
  const float4* src = (const float4*)(ego + (long long)cl * D);
  float4 m = src[c];
  float* dst = side + (long long)r * D + c * 4;
  atomicAdd(dst + 0, v * m.x);
  atomicAdd(dst + 1, v * m.y);
  atomicAdd(dst + 2, v * m.z);
  atomicAdd(dst + 3, v * m.w);
}

__global__ __launch_bounds__(128) void transform_f32_kernel(
    const float* __restrict__ side,
    const float* __restrict__ ego,
    const float* __restrict__ w_gc,
    const float* __restrict__ b_gc,
    const float* __restrict__ w_bi,
    const float* __restrict__ b_bi,
    float*       __restrict__ out) {
  constexpr int RPB = 16;
  __shared__ float s_side[RPB][D];
  __shared__ float s_prod[RPB][D];
  __shared__ float s_part[RPB][2];
  const int j    = threadIdx.x;
  const int base = blockIdx.x * RPB;
  #pragma unroll
  for (int r = 0; r < RPB; ++r) {
    int node = base + r;
    float s = 0.f, e = 0.f;
    if (node < N_NODES) {
      s = side[(long long)node * D + j];
      e = ego [(long long)node * D + j];
    }
    s_side[r][j] = s;
    s_prod[r][j] = e * s;
  }
  __syncthreads();
  float acc_gc[RPB], acc_bi[RPB];
  #pragma unroll
  for (int r = 0; r < RPB; ++r) { acc_gc[r] = 0.f; acc_bi[r] = 0.f; }
  for (int k = 0; k < D; ++k) {
    float wg = w_gc[k * D + j];
    float wb = w_bi[k * D + j];
    #pragma unroll
    for (int r = 0; r < RPB; ++r) {
      acc_gc[r] = fmaf(s_side[r][k], wg, acc_gc[r]);
      acc_bi[r] = fmaf(s_prod[r][k], wb, acc_bi[r]);
    }
  }
  const float bg = b_gc[j];
  const float bb = b_bi[j];
  #pragma unroll
  for (int r = 0; r < RPB; ++r) {
    float x1 = acc_gc[r] + bg; x1 = (x1 > 0.f) ? x1 : LEAKY * x1;
    float x2 = acc_bi[r] + bb; x2 = (x2 > 0.f) ? x2 : LEAKY * x2;
    acc_gc[r] = x1 + x2;
  }
  const int lane = j & 63;
  const int wv   = j >> 6;
  #pragma unroll
  for (int r = 0; r < RPB; ++r) {
    float sq = acc_gc[r] * acc_gc[r];
    #pragma unroll
    for (int off = 32; off > 0; off >>= 1) sq += __shfl_down(sq, off, 64);
    if (lane == 0) s_part[r][wv] = sq;
  }
  __syncthreads();
  #pragma unroll
  for (int r = 0; r < RPB; ++r) {
    int node = base + r;
    if (node < N_NODES) {
      float tot = s_part[r][0] + s_part[r][1];
      float inv = rsqrtf(fmaxf(tot, L2EPS));
      out[(long long)node * D + j] = acc_gc[r] * inv;
    }
  }
}

// ===========================================================================
extern "C" void kernel_launch(void* const* d_in, const int* in_sizes, int n_in,
                              void* d_out, int out_size, void* d_ws, size_t ws_size,
                              hipStream_t stream) {
  const int*   erow = (const int*)  d_in[0];
  const int*   ecol = (const int*)  d_in[1];
  const float* eval = (const float*)d_in[2];
  const float* ego  = (const float*)d_in[3];
  const float* w_gc = (const float*)d_in[4];
  const float* b_gc = (const float*)d_in[5];
  const float* w_bi = (const float*)d_in[6];
  const float* b_bi = (const float*)d_in[7];
  float* out = (float*)d_out;

  auto align256 = [](size_t x) { return (x + 255) & ~(size_t)255; };
  size_t off_cnt    = 0;
  size_t off_offs   = align256(off_cnt    + (size_t)N_NODES * 4);
  size_t off_cursor = align256(off_offs   + (size_t)(N_NODES + 1) * 4);
  size_t off_bsums  = align256(off_cursor + (size_t)N_NODES * 4);
  size_t off_bcur   = align256(off_bsums  + 1024 * 4);
  size_t off_wtg    = align256(off_bcur   + (size_t)NBK * 4);
  size_t off_wtb    = align256(off_wtg    + (size_t)D * D * 2);
  size_t off_ev     = align256(off_wtb    + (size_t)D * D * 2);
  size_t off_ebf    = align256(off_ev     + (size_t)N_EDGES * 8);
  size_t ws_mid     = off_ebf;                                   // old bin tier
  size_t ws_sort    = off_ebf + (size_t)N_EDGES * 8;             // bucketed sort, fp32 ego
  size_t ws_full    = off_ebf + (size_t)N_NODES * D * 2;         // + bf16 ego

  if (ws_size >= ws_mid) {
    char* ws = (char*)d_ws;
    int*   cnt    = (int*)  (ws + off_cnt);
    int*   offs   = (int*)  (ws + off_offs);
    int*   cursor = (int*)  (ws + off_cursor);
    int*   bsums  = (int*)  (ws + off_bsums);
    int*   bcur   = (int*)  (ws + off_bcur);
    short* wtg    = (short*)(ws + off_wtg);
    short* wtb    = (short*)(ws + off_wtb);
    int2*  ev     = (int2*) (ws + off_ev);
    short* ebf    = (short*)(ws + off_ebf);
    int2*  stage  = (int2*) (ws + off_ebf);   // aliases ebf; consumed before conv_ego

    float* side = out;   // alias: spmm writes all rows; transform is row-local

    hipMemsetAsync(cnt, 0, (size_t)N_NODES * 4, stream);

    hist_kernel<<<(N_EDGES + 2047) / 2048, 256, 0, stream>>>(erow, cnt);
    scan_block_sums<<<NB_SCAN, 256, 0, stream>>>(cnt, bsums);
    scan_partials<<<1, 1024, 0, stream>>>(bsums);
    scan_final<<<NB_SCAN, 256, 0, stream>>>(cnt, bsums, offs, cursor, bcur);

    bool bucketed = (ws_size >= ws_sort);
    if (bucketed) {
      bucket_scatter_kernel<<<(N_EDGES + EPB_A - 1) / EPB_A, 256, 0, stream>>>(
          erow, ecol, eval, bcur, stage);
      bucket_permute_kernel<<<NBK, 256, 0, stream>>>(offs, stage, ev);
    } else {
      bin_kernel<<<(N_EDGES + 1023) / 1024, 256, 0, stream>>>(
          erow, ecol, eval, cursor, ev);
    }
    prep_weights_kernel<<<D, D, 0, stream>>>(w_gc, w_bi, wtg, wtb);

    if (ws_size >= ws_full) {
      conv_ego_kernel<<<(N_NODES * D / 4 + 255) / 256, 256, 0, stream>>>(ego, ebf);
      spmm_bf16_kernel<<<N_NODES / 16, 256, 0, stream>>>(offs, ev, ebf, side);
    } else {
      spmm_kernel<<<(N_NODES + 7) / 8, 256, 0, stream>>>(offs, ev, ego, side);
    }
    transform_mfma_kernel<<<N_NODES / 16, 256, 0, stream>>>(
        side, ego, wtg, wtb, b_gc, b_bi, out);
  } else {
    float* side = out;
    hipMemsetAsync(side, 0, (size_t)N_NODES * D * 4, stream);
    long long total = (long long)N_EDGES * 32;
    int grid = (int)((total + 255) / 256);
    scatter_kernel<<<grid, 256, 0, stream>>>(erow, ecol, eval, ego, side);
    transform_f32_kernel<<<N_NODES / 16, 128, 0, stream>>>(
        side, ego, w_gc, b_gc, w_bi, b_bi, out);
  }
}